// Round 10
// baseline (432.875 us; speedup 1.0000x reference)
//
#include <hip/hip_runtime.h>
#include <hip/hip_bf16.h>

typedef __bf16 bf16x8 __attribute__((ext_vector_type(8)));
typedef float f32x4 __attribute__((ext_vector_type(4)));

// FREE-RUNNING TLP DESIGN (no per-pass barriers, no staging pipeline):
//  - grid = 256 blocks (1 per CU, forced by 128.5 KB LDS), block = 1024 thr.
//  - Init phase: block cooperatively converts clusters -> bf16 into LDS
//    (XOR-swizzled) + fp32 c2[128]; ONE __syncthreads; LDS read-only after.
//  - Main phase: 16 waves free-run. Each wave owns 32 rows (2 tiles x 16).
//    x is loaded straight into MFMA fragment layout (lane (m,g) reads row m,
//    k-seg g) with a 2-step register ping-pong; B fragments come from LDS.
//    All normalization is wave-local (wave owns all 128 columns).
//  - Rationale: every barrier-lockstep variant (R3-R9) pinned avg outstanding
//    reads/CU at ~13 KB < 22 KB BDP -> 3.8 TB/s plateau. 16 desynced waves
//    issuing independently keep the memory pipe busy continuously.
__global__ __launch_bounds__(1024)
void cluster_q_fused(const float* __restrict__ x,
                     const float* __restrict__ c,
                     float* __restrict__ out)
{
    __shared__ __align__(16) unsigned char Blds[131072];  // 128 cols x 512 k bf16
    __shared__ float c2_lds[128];

    const int tid = threadIdx.x;
    const int l = tid & 63;
    const int wv = tid >> 6;          // wave 0..15

    // ---- init: B (bf16, swizzled) + c2 ----
    // Wave wv handles cols wv*8..wv*8+7; lane l: col wv*8+(l>>3), k (l&7)*64..+64.
    {
        const int col = wv * 8 + (l >> 3);
        const float* p = c + col * 512 + (l & 7) * 64;
        float s = 0.f;
#pragma unroll
        for (int j = 0; j < 8; ++j) {
            f32x4 u0 = *(const f32x4*)(p + j * 8);
            f32x4 u1 = *(const f32x4*)(p + j * 8 + 4);
            bf16x8 v;
#pragma unroll
            for (int i = 0; i < 4; ++i) {
                v[i]     = (__bf16)u0[i];
                v[4 + i] = (__bf16)u1[i];
                s += u0[i] * u0[i] + u1[i] * u1[i];
            }
            const int ci = (l & 7) * 8 + j;            // 16B chunk within col
            *(bf16x8*)(Blds + col * 1024 + ((ci ^ (col & 7)) * 16)) = v;
        }
        s += __shfl_xor(s, 1);
        s += __shfl_xor(s, 2);
        s += __shfl_xor(s, 4);
        if ((l & 7) == 0) c2_lds[col] = s;
    }
    __syncthreads();          // the ONLY block-wide barrier

    const int m = l & 15;     // fragment row (A) / col (B)
    const int g = l >> 4;     // k-group 0..3
    const long rbase0 = (long)blockIdx.x * 512 + wv * 32;

    float c2v[8];
#pragma unroll
    for (int nb = 0; nb < 8; ++nb) c2v[nb] = c2_lds[nb * 16 + m];

#pragma unroll 1
    for (int t16 = 0; t16 < 2; ++t16) {
        const long rbase = rbase0 + t16 * 16;
        const float* ab = x + (rbase + m) * 512 + g * 8;

        f32x4 acc[8];
#pragma unroll
        for (int nb = 0; nb < 8; ++nb) acc[nb] = f32x4{0.f, 0.f, 0.f, 0.f};
        float x2p = 0.f;

        // 2-deep ks ping-pong (fully unrolled loop -> static indices).
        f32x4 P[2][2];
        P[0][0] = *(const f32x4*)(ab);
        P[0][1] = *(const f32x4*)(ab + 4);
        P[1][0] = *(const f32x4*)(ab + 32);
        P[1][1] = *(const f32x4*)(ab + 36);

#pragma unroll
        for (int ks = 0; ks < 16; ++ks) {
            const int sl = ks & 1;
            f32x4 u0 = P[sl][0], u1 = P[sl][1];
            if (ks < 14) {
                P[sl][0] = *(const f32x4*)(ab + (ks + 2) * 32);
                P[sl][1] = *(const f32x4*)(ab + (ks + 2) * 32 + 4);
            }
            bf16x8 aF;
#pragma unroll
            for (int i = 0; i < 4; ++i) {
                aF[i]     = (__bf16)u0[i];
                aF[4 + i] = (__bf16)u1[i];
                x2p += u0[i] * u0[i] + u1[i] * u1[i];
            }
#pragma unroll
            for (int nb = 0; nb < 8; ++nb) {
                bf16x8 bF = *(const bf16x8*)(
                    Blds + (nb * 16 + m) * 1024
                         + (((ks * 4 + g) ^ (m & 7)) * 16));
                acc[nb] = __builtin_amdgcn_mfma_f32_16x16x32_bf16(
                    aF, bF, acc[nb], 0, 0, 0);
            }
        }

        // Wave-local epilogue: complete x2, q, row sums, normalize, store.
        x2p += __shfl_xor(x2p, 16);
        x2p += __shfl_xor(x2p, 32);
        float x2r[4], rs[4];
#pragma unroll
        for (int r = 0; r < 4; ++r) {
            x2r[r] = __shfl(x2p, g * 4 + r);   // row (g*4+r) of this tile
            rs[r] = 0.f;
        }
#pragma unroll
        for (int nb = 0; nb < 8; ++nb)
#pragma unroll
            for (int r = 0; r < 4; ++r) {
                float d2 = fmaxf(x2r[r] + c2v[nb] - 2.f * acc[nb][r], 0.f);
                float qv = __builtin_amdgcn_rcpf(1.f + d2);   // ALPHA=1
                acc[nb][r] = qv;
                rs[r] += qv;
            }
#pragma unroll
        for (int r = 0; r < 4; ++r) {
            rs[r] += __shfl_xor(rs[r], 1);
            rs[r] += __shfl_xor(rs[r], 2);
            rs[r] += __shfl_xor(rs[r], 4);
            rs[r] += __shfl_xor(rs[r], 8);
            rs[r] = __builtin_amdgcn_rcpf(rs[r]);
        }
        const long orow = rbase + g * 4;
#pragma unroll
        for (int r = 0; r < 4; ++r)
#pragma unroll
            for (int nb = 0; nb < 8; ++nb)
                out[(orow + r) * 128 + nb * 16 + m] = acc[nb][r] * rs[r];
    }
}

extern "C" void kernel_launch(void* const* d_in, const int* in_sizes, int n_in,
                              void* d_out, int out_size, void* d_ws, size_t ws_size,
                              hipStream_t stream)
{
    const float* x = (const float*)d_in[0];
    const float* c = (const float*)d_in[1];
    float* out = (float*)d_out;
    const int N = in_sizes[0] / 512;            // 131072 rows
    dim3 grid(N / 512), block(1024);            // 256 blocks = 1 per CU
    hipLaunchKernelGGL(cluster_q_fused, grid, block, 0, stream, x, c, out);
}

// Round 11
// 65.927 us; speedup vs baseline: 6.5659x; 6.5659x over previous
//
#include <hip/hip_runtime.h>
#include <hip/hip_bf16.h>

typedef __bf16 bf16x8 __attribute__((ext_vector_type(8)));
typedef float f32x4 __attribute__((ext_vector_type(4)));

// Pre-kernel: clusters (128x512 f32) -> bf16 in ws, plus fp32 c2[128].
__global__ __launch_bounds__(64)
void prep_clusters(const float* __restrict__ c, __bf16* __restrict__ cb,
                   float* __restrict__ c2)
{
    const int row = blockIdx.x;     // 0..127
    const int l = threadIdx.x;      // 0..63
    const float* p = c + row * 512 + l * 8;
    f32x4 u0 = *(const f32x4*)p;
    f32x4 u1 = *(const f32x4*)(p + 4);
    bf16x8 v;
    float s = 0.f;
#pragma unroll
    for (int j = 0; j < 4; ++j) {
        v[j]     = (__bf16)u0[j];
        v[4 + j] = (__bf16)u1[j];
        s += u0[j] * u0[j] + u1[j] * u1[j];
    }
    *(bf16x8*)(cb + row * 512 + l * 8) = v;
#pragma unroll
    for (int off = 32; off >= 1; off >>= 1) s += __shfl_xor(s, off);
    if (l == 0) c2[row] = s;
}

// R8 base (82 us: reg-staged streaming, single G-set, persistent-B) with ONE
// change, driven by R10's counters (WRITE_SIZE 595 MB vs 64 MB ideal = 9.3x
// partial-line write amplification): the epilogue's 32 scalar 4B stores are
// replaced by FULL-LINE writes. q is bounced through a wave-private 2KB LDS
// tile (XOR-swizzled, no new barriers) and stored with 2 nontemporal
// global_store_dwordx4 per lane — each store instruction covers 1KB
// contiguous (8 complete 128B lines). vmcnt(8) -> vmcnt(2) (2-store epilogue:
// keep the 2 newest stores, drain all 8 staged loads; in-order retirement).
__global__ __launch_bounds__(256, 2)
void cluster_q_mfma(const float* __restrict__ x,
                    const __bf16* __restrict__ cb,
                    const float* __restrict__ c2,
                    float* __restrict__ out)
{
    __shared__ float lds[16 * 512];      // one 32 KB tile (16 rows x 512)
    __shared__ float rsx[4][16];         // per-wave partial row sums
    __shared__ float qt[4][16 * 32];     // per-wave q transpose tile (2 KB)

    const int tid = threadIdx.x;
    const int l = tid & 63;
    const int w = tid >> 6;         // wave 0..3: owns cols w*32 .. w*32+31
    const int m = l & 15;           // fragment row (A) / col (B)
    const int g = l >> 4;           // k-group 0..3
    const long brow = (long)blockIdx.x * 256;

    float c2v[2];
#pragma unroll
    for (int nb = 0; nb < 2; ++nb) c2v[nb] = c2[w * 32 + nb * 16 + m];

    // Persistent B: cols w*32+nb*16+m, all 512 k. 32 x b128 loads, 128 VGPRs.
    bf16x8 bR[2][16];
#pragma unroll
    for (int nb = 0; nb < 2; ++nb)
#pragma unroll
        for (int ks = 0; ks < 16; ++ks)
            bR[nb][ks] = *(const bf16x8*)(
                cb + (w * 32 + nb * 16 + m) * 512 + ks * 32 + g * 8);

    // Staging geometry (unchanged from R8): instr i_ covers tile-row
    // w*4+(i_>>1), half h=i_&1; lane l takes chunk l of the 1KB half (linear).
    int cow[4];
#pragma unroll
    for (int q = 0; q < 4; ++q)
        cow[q] = (l & 56) + ((l & 7) ^ ((w * 4 + q) & 7));

    // LDS read bases (bytes): row m, chunk (ks*8 + (2g|2g+1)^(m&7)).
    const int rbo0 = m * 2048 + (((2 * g)     ^ (m & 7)) * 16);
    const int rbo1 = m * 2048 + (((2 * g + 1) ^ (m & 7)) * 16);

    // Output read-back geometry: 2 instructions of 8 rows x 8 chunks.
    const int orow_l = l >> 3;      // row within 8-row half
    const int opos = l & 7;         // 16B chunk position within 32-col piece

    f32x4 G[8];

#define SB __builtin_amdgcn_sched_barrier(0)
#define GLOAD(P)                                                          \
    { _Pragma("unroll")                                                   \
      for (int i_ = 0; i_ < 8; ++i_)                                      \
          G[i_] = *(const f32x4*)(x + (brow + (long)(P) * 16              \
                     + w * 4 + (i_ >> 1)) * 512 + (i_ & 1) * 256 + l * 4); }
#define DSWRITE()                                                         \
    { _Pragma("unroll")                                                   \
      for (int i_ = 0; i_ < 8; ++i_)                                      \
          *(f32x4*)(&lds[(w * 4 + (i_ >> 1)) * 512 + (i_ & 1) * 256       \
                         + cow[i_ >> 1] * 4]) = G[i_]; }

    // Prologue: tile 0 through registers into LDS.
    GLOAD(0);
    asm volatile("s_waitcnt vmcnt(0)" ::: "memory");
    DSWRITE();
    asm volatile("s_waitcnt lgkmcnt(0)" ::: "memory");
    __builtin_amdgcn_s_barrier();

#pragma unroll 1
    for (int p = 0; p < 16; ++p) {
        // P1: issue next tile's loads early (latency hides under compute).
        if (p < 15) { GLOAD(p + 1); }
        SB;

        // P2: compute pass p from LDS.
        f32x4 acc[2] = {f32x4{0.f, 0.f, 0.f, 0.f}, f32x4{0.f, 0.f, 0.f, 0.f}};
        float x2p = 0.f;
        const char* L = (const char*)&lds[0];
#pragma unroll
        for (int ks = 0; ks < 16; ++ks) {
            f32x4 u0 = *(const f32x4*)(L + rbo0 + ks * 128);
            f32x4 u1 = *(const f32x4*)(L + rbo1 + ks * 128);
            bf16x8 aF;
#pragma unroll
            for (int j = 0; j < 4; ++j) {
                aF[j]     = (__bf16)u0[j];
                aF[4 + j] = (__bf16)u1[j];
                x2p += u0[j] * u0[j] + u1[j] * u1[j];
            }
            acc[0] = __builtin_amdgcn_mfma_f32_16x16x32_bf16(aF, bR[0][ks], acc[0], 0, 0, 0);
            acc[1] = __builtin_amdgcn_mfma_f32_16x16x32_bf16(aF, bR[1][ks], acc[1], 0, 0, 0);
        }

        // P3: epilogue for these 16 rows.
        x2p += __shfl_xor(x2p, 16);
        x2p += __shfl_xor(x2p, 32);

        float x2r[4], rs[4];
#pragma unroll
        for (int r = 0; r < 4; ++r) {
            x2r[r] = __shfl(x2p, g * 4 + r);
            rs[r] = 0.f;
        }
#pragma unroll
        for (int nb = 0; nb < 2; ++nb)
#pragma unroll
            for (int r = 0; r < 4; ++r) {
                float d2 = fmaxf(x2r[r] + c2v[nb] - 2.f * acc[nb][r], 0.f);
                float qv = __builtin_amdgcn_rcpf(1.f + d2);  // ALPHA=1
                acc[nb][r] = qv;
                rs[r] += qv;
            }
#pragma unroll
        for (int r = 0; r < 4; ++r) {
            rs[r] += __shfl_xor(rs[r], 1);
            rs[r] += __shfl_xor(rs[r], 2);
            rs[r] += __shfl_xor(rs[r], 4);
            rs[r] += __shfl_xor(rs[r], 8);
        }
        if (m == 0) {
#pragma unroll
            for (int r = 0; r < 4; ++r) rsx[w][g * 4 + r] = rs[r];
        }
        asm volatile("s_waitcnt lgkmcnt(0)" ::: "memory");
        __builtin_amdgcn_s_barrier();      // BARRIER-A: rsx ready, tile reads done

        // Normalize -> wave-private qt (XOR-swizzled chunks) -> 2 full-line
        // nontemporal 1KB store instructions.
#pragma unroll
        for (int r = 0; r < 4; ++r) {
            const int row16 = g * 4 + r;
            const float inv = __builtin_amdgcn_rcpf(
                rsx[0][row16] + rsx[1][row16] + rsx[2][row16] + rsx[3][row16]);
#pragma unroll
            for (int nb = 0; nb < 2; ++nb) {
                const int chunk = nb * 4 + (m >> 2);
                qt[w][row16 * 32 + ((chunk ^ (row16 & 7)) * 4) + (m & 3)] =
                    acc[nb][r] * inv;
            }
        }
        // wave-private RAW: compiler inserts the lgkmcnt for qt reads below.
        const long obase = brow + p * 16;
#pragma unroll
        for (int h = 0; h < 2; ++h) {
            const int row16 = h * 8 + orow_l;
            f32x4 v = *(const f32x4*)&qt[w][row16 * 32 +
                                            ((opos ^ (row16 & 7)) * 4)];
            __builtin_nontemporal_store(
                v, (f32x4*)(out + (obase + row16) * 128 + w * 32 + opos * 4));
        }
        SB;

        // P4: land next tile in LDS. vmcnt(2): keep the 2 newest (this pass's
        // stores), drain all 8 staged loads (in-order retirement).
        if (p < 15) {
            asm volatile("s_waitcnt vmcnt(2)" ::: "memory");
            SB;
            DSWRITE();
            asm volatile("s_waitcnt lgkmcnt(0)" ::: "memory");
            __builtin_amdgcn_s_barrier();  // BARRIER-B: tile p+1 visible to all
        }
    }
#undef GLOAD
#undef DSWRITE
#undef SB
}

extern "C" void kernel_launch(void* const* d_in, const int* in_sizes, int n_in,
                              void* d_out, int out_size, void* d_ws, size_t ws_size,
                              hipStream_t stream)
{
    const float* x = (const float*)d_in[0];
    const float* c = (const float*)d_in[1];
    float* out = (float*)d_out;

    float*  c2ws = (float*)d_ws;                        // 128 floats
    __bf16* cbws = (__bf16*)((char*)d_ws + 1024);       // 128x512 bf16 = 128 KB

    hipLaunchKernelGGL(prep_clusters, dim3(128), dim3(64), 0, stream, c, cbws, c2ws);

    const int N = in_sizes[0] / 512;                    // 131072 rows
    dim3 grid(N / 256), block(256);                     // 512 blocks = 2/CU
    hipLaunchKernelGGL(cluster_q_mfma, grid, block, 0, stream, x, cbws, c2ws, out);
}